// Round 6
// baseline (86.565 us; speedup 1.0000x reference)
//
#include <hip/hip_runtime.h>
#include <math.h>

// CapLayer fused: grouped 1x1 conv + 3-iter dynamic routing.
// R6: grid 512 (one block = one b x 5 consecutive j). R4/R5 showed ~0.85
// blocks/CU resident regardless of occupancy limits -> per-block latency and
// dispatch count dominate. So: longer blocks, x kept in regs across 5 j,
// W double-buffered in LDS with prefetch issued BEFORE pred compute (latency
// hidden under FMAs), consumed ~6 barriers later. bias via broadcast global
// loads (no LDS staging). No launch_bounds min-waves (R2/R3: caps below the
// ~80-reg working set cause 264-353 MB scratch spills).
// Ws padded to 132 f/group (R4: unpadded 512B stride = 6-way ds conflicts).

#define G_     32
#define IND_   8
#define J_     10
#define D_     16
#define S_     36
#define NT_    576
#define NW_    (NT_ / 64)    // 9
#define WPAD_  132
#define JCH_   5             // j's per block

__global__ __launch_bounds__(NT_) void caps_route_kernel(
    const float* __restrict__ x,     // (b, g*8+id, s)
    const float* __restrict__ Wt,    // (g, j*16+d, id)
    const float* __restrict__ bias,  // g*160 + j*16 + d
    float* __restrict__ out)         // (b, j, d)
{
    // XCD swizzle: consecutive blocks (same/neighboring b) share an XCD L2
    const int B = blockIdx.x;
    const int nwg = gridDim.x;
    const int idx = ((nwg & 7) == 0) ? (B & 7) * (nwg >> 3) + (B >> 3) : B;
    const int b = idx >> 1;
    const int jbase = (idx & 1) * JCH_;
    const int t = threadIdx.x;
    const int lane = t & 63;
    const int wid = t >> 6;

    __shared__ __align__(16) float Ws[2][G_ * WPAD_];   // 2 x 16.9 KB, (g, d*8+id) padded
    __shared__ __align__(16) float pt[2][NW_][D_];
    __shared__ float sm[2][NW_];
    __shared__ __align__(16) float sv[2][D_];

    const int g = t / 18;               // thread owns i = 2t, 2t+1 within group g
    const int r = t - g * 18;
    const float* xb = x + (size_t)b * (G_ * IND_ * S_) + g * (IND_ * S_) + 2 * r;

    // ---- x once per block, lives in regs across all 5 j ----
    float2 xq[IND_];
    #pragma unroll
    for (int id = 0; id < IND_; ++id) xq[id] = *(const float2*)(xb + id * S_);

    // ---- stage W for first j into Ws[0] ----
    for (int i2 = t; i2 < G_ * 32; i2 += NT_) {
        const int gg = i2 >> 5, rr = i2 & 31;
        ((float4*)(Ws[0] + gg * WPAD_))[rr] =
            *(const float4*)(Wt + (size_t)gg * (J_ * D_ * IND_) + jbase * (D_ * IND_) + rr * 4);
    }
    __syncthreads();

    const float EPS = 2.220446049250313e-16f;
    const bool hib5 = (lane & 32) != 0, hib4 = (lane & 16) != 0;
    const bool hib3 = (lane & 8) != 0,  hib2 = (lane & 4) != 0;

    #pragma unroll 1
    for (int jj = 0; jj < JCH_; ++jj) {
        const int j = jbase + jj;
        const int cur = jj & 1;

        // issue next-j W prefetch loads EARLY (land during pred compute)
        float4 wv0, wv1;
        const bool pf = (jj + 1 < JCH_) && (t < 512);
        int pg0 = 0, pr0 = 0, pg1 = 0, pr1 = 0;
        if (pf) {
            pg0 = t >> 5;          pr0 = t & 31;
            pg1 = (t + 512) >> 5;  pr1 = (t + 512) & 31;
            wv0 = *(const float4*)(Wt + (size_t)pg0 * (J_ * D_ * IND_) + (j + 1) * (D_ * IND_) + pr0 * 4);
            wv1 = *(const float4*)(Wt + (size_t)pg1 * (J_ * D_ * IND_) + (j + 1) * (D_ * IND_) + pr1 * 4);
        }
        // bias for this (g, j): 16 consecutive floats, broadcast within group
        const float4* bgp = (const float4*)(bias + (size_t)g * (J_ * D_) + j * D_);
        const float4 bb0 = bgp[0], bb1 = bgp[1], bb2 = bgp[2], bb3 = bgp[3];

        // ---- pred[d][q] from Ws[cur] ----
        float pred[D_][2];
        {
            const float4* wp = (const float4*)(Ws[cur] + g * WPAD_);
            #pragma unroll
            for (int d = 0; d < D_; ++d) {
                const float4 w0 = wp[d * 2 + 0];
                const float4 w1 = wp[d * 2 + 1];
                float bv;
                if (d < 4)       bv = (d == 0) ? bb0.x : (d == 1) ? bb0.y : (d == 2) ? bb0.z : bb0.w;
                else if (d < 8)  bv = (d == 4) ? bb1.x : (d == 5) ? bb1.y : (d == 6) ? bb1.z : bb1.w;
                else if (d < 12) bv = (d == 8) ? bb2.x : (d == 9) ? bb2.y : (d == 10) ? bb2.z : bb2.w;
                else             bv = (d == 12) ? bb3.x : (d == 13) ? bb3.y : (d == 14) ? bb3.z : bb3.w;
                pred[d][0] = bv
                    + w0.x * xq[0].x + w0.y * xq[1].x + w0.z * xq[2].x + w0.w * xq[3].x
                    + w1.x * xq[4].x + w1.y * xq[5].x + w1.z * xq[6].x + w1.w * xq[7].x;
                pred[d][1] = bv
                    + w0.x * xq[0].y + w0.y * xq[1].y + w0.z * xq[2].y + w0.w * xq[3].y
                    + w1.x * xq[4].y + w1.y * xq[5].y + w1.z * xq[6].y + w1.w * xq[7].y;
            }
        }

        // write prefetched W into the other buffer (safe: all waves passed the
        // previous jj's routing barriers before any thread reaches here)
        if (pf) {
            ((float4*)(Ws[cur ^ 1] + pg0 * WPAD_))[pr0] = wv0;
            ((float4*)(Ws[cur ^ 1] + pg1 * WPAD_))[pr1] = wv1;
        }

        // ---- routing ----
        float b_loc[2] = {0.f, 0.f};

        #pragma unroll 1
        for (int it = 0; it < 3; ++it) {
            const int k = it & 1;

            float e0, e1, se;
            if (it == 0) {
                e0 = e1 = 1.f; se = 2.f;
            } else {
                e0 = __expf(b_loc[0]); e1 = __expf(b_loc[1]); se = e0 + e1;
            }
            #pragma unroll
            for (int off = 32; off >= 1; off >>= 1) se += __shfl_xor(se, off);
            if (lane == 0) sm[k][wid] = se;

            float p[D_];
            #pragma unroll
            for (int d = 0; d < D_; ++d)
                p[d] = e0 * pred[d][0] + e1 * pred[d][1];

            // packed butterfly: one shfl per exchange; lane l ends with d = l>>2
            float q8[8];
            #pragma unroll
            for (int dd = 0; dd < 8; ++dd) {
                const float snd = hib5 ? p[dd] : p[dd + 8];
                const float rr  = __shfl_xor(snd, 32);
                q8[dd] = (hib5 ? p[dd + 8] : p[dd]) + rr;
            }
            float q4[4];
            #pragma unroll
            for (int dd = 0; dd < 4; ++dd) {
                const float snd = hib4 ? q8[dd] : q8[dd + 4];
                const float rr  = __shfl_xor(snd, 16);
                q4[dd] = (hib4 ? q8[dd + 4] : q8[dd]) + rr;
            }
            float q2[2];
            #pragma unroll
            for (int dd = 0; dd < 2; ++dd) {
                const float snd = hib3 ? q4[dd] : q4[dd + 2];
                const float rr  = __shfl_xor(snd, 8);
                q2[dd] = (hib3 ? q4[dd + 2] : q4[dd]) + rr;
            }
            float q1;
            {
                const float snd = hib2 ? q2[0] : q2[1];
                const float rr  = __shfl_xor(snd, 4);
                q1 = (hib2 ? q2[1] : q2[0]) + rr;
            }
            q1 += __shfl_xor(q1, 2);
            q1 += __shfl_xor(q1, 1);
            if ((lane & 3) == 0) pt[k][wid][lane >> 2] = q1;
            __syncthreads();                                   // barrier A

            float denom = 0.f;
            #pragma unroll
            for (int w = 0; w < NW_; ++w) denom += sm[k][w];

            if (t < D_) {
                float ss = 0.f;
                #pragma unroll
                for (int w = 0; w < NW_; ++w) ss += pt[k][w][t];
                sv[k][t] = ss;
            }
            __syncthreads();                                   // barrier B

            const float4 s0v = ((const float4*)sv[k])[0];
            const float4 s1v = ((const float4*)sv[k])[1];
            const float4 s2v = ((const float4*)sv[k])[2];
            const float4 s3v = ((const float4*)sv[k])[3];
            float ssq = s0v.x * s0v.x + s0v.y * s0v.y + s0v.z * s0v.z + s0v.w * s0v.w
                      + s1v.x * s1v.x + s1v.y * s1v.y + s1v.z * s1v.z + s1v.w * s1v.w
                      + s2v.x * s2v.x + s2v.y * s2v.y + s2v.z * s2v.z + s2v.w * s2v.w
                      + s3v.x * s3v.x + s3v.y * s3v.y + s3v.z * s3v.z + s3v.w * s3v.w;
            const float alpha = 1.0f / denom;
            const float n2 = ssq * alpha * alpha;
            const float norm = sqrtf(n2);
            const float coeff = (n2 / (1.f + n2)) / (norm + EPS);
            const float beta = alpha * coeff;   // v[d] = sv[d] * beta

            if (it < 2) {
                #pragma unroll
                for (int q = 0; q < 2; ++q) {
                    float dot =
                        s0v.x * pred[0][q]  + s0v.y * pred[1][q]  + s0v.z * pred[2][q]  + s0v.w * pred[3][q]
                      + s1v.x * pred[4][q]  + s1v.y * pred[5][q]  + s1v.z * pred[6][q]  + s1v.w * pred[7][q]
                      + s2v.x * pred[8][q]  + s2v.y * pred[9][q]  + s2v.z * pred[10][q] + s2v.w * pred[11][q]
                      + s3v.x * pred[12][q] + s3v.y * pred[13][q] + s3v.z * pred[14][q] + s3v.w * pred[15][q];
                    b_loc[q] += beta * dot;
                }
            } else {
                if (t < D_) out[((size_t)b * J_ + j) * D_ + t] = sv[k][t] * beta;
            }
        }
    }
}

extern "C" void kernel_launch(void* const* d_in, const int* in_sizes, int n_in,
                              void* d_out, int out_size, void* d_ws, size_t ws_size,
                              hipStream_t stream) {
    const float* x    = (const float*)d_in[0];
    const float* Wt   = (const float*)d_in[1];
    const float* bias = (const float*)d_in[2];
    float* out        = (float*)d_out;

    const int bs = in_sizes[0] / (G_ * IND_ * S_);   // 256
    dim3 grid(bs * (J_ / JCH_));                     // 512 blocks
    dim3 block(NT_);
    caps_route_kernel<<<grid, block, 0, stream>>>(x, Wt, bias, out);
}

// Round 7
// 68.416 us; speedup vs baseline: 1.2653x; 1.2653x over previous
//
#include <hip/hip_runtime.h>
#include <math.h>

// CapLayer fused: grouped 1x1 conv + 3-iter dynamic routing.
// R7: NT=192 (3 waves), QN=6 (i = 6t..6t+5, group g = t/6). Same 16-waves/CU
// VGPR bin as R4 (96 regs) but as 5.3 independent blocks/CU instead of 2.67 ->
// barrier stalls of one block hide under 4+ others. launch_bounds(192,4) caps
// VGPR at 128, just ABOVE the ~120-126 working set (R2/R3/R6 lesson: caps
// below the working set cause 60-350 MB scratch spills; watch WRITE_SIZE).
// it=0 specialized: denom = 1152 exactly, no exp / no se reduce / no sm LDS.
// Ws padded to 132 f/group (R4: unpadded 512B stride = 6-way ds conflicts).

#define G_     32
#define IND_   8
#define J_     10
#define D_     16
#define S_     36
#define NT_    192
#define QN_    6
#define NW_    (NT_ / 64)    // 3
#define WPAD_  132
#define BPAD_  17

__global__ __launch_bounds__(NT_, 4) void caps_route_kernel(
    const float* __restrict__ x,     // (b, g*8+id, s)
    const float* __restrict__ Wt,    // (g, j*16+d, id)
    const float* __restrict__ bias,  // g*160 + j*16 + d
    float* __restrict__ out)         // (b, j, d)
{
    // XCD swizzle: consecutive bj (same b, all j) land on one XCD for L2 x-reuse
    const int B = blockIdx.x;
    const int nwg = gridDim.x;
    const int bj = ((nwg & 7) == 0) ? (B & 7) * (nwg >> 3) + (B >> 3) : B;
    const int b = bj / J_;
    const int j = bj - b * J_;
    const int t = threadIdx.x;
    const int lane = t & 63;
    const int wid = t >> 6;

    __shared__ __align__(16) float Ws[G_ * WPAD_];   // 16.9 KB (g, d*8+id) padded
    __shared__ float bs_[G_ * BPAD_];                // 2.2 KB
    __shared__ __align__(16) float pt[2][NW_][D_];
    __shared__ float sm[2][NW_];
    __shared__ __align__(16) float sv[2][D_];

    const int g  = t / 6;               // 6 threads per group; i = 6t + q
    const int s0 = 6 * (t - g * 6);
    const float* xb = x + (size_t)b * (G_ * IND_ * S_) + g * (IND_ * S_) + s0;

    // ---- stage W j-slice (contiguous 128 floats per g, padded dst) + bias ----
    for (int idx = t; idx < G_ * 32; idx += NT_) {
        const int gg = idx >> 5, rr = idx & 31;
        ((float4*)(Ws + gg * WPAD_))[rr] =
            *(const float4*)(Wt + (size_t)gg * (J_ * D_ * IND_) + j * (D_ * IND_) + rr * 4);
    }
    for (int idx = t; idx < G_ * D_; idx += NT_) {
        const int gg = idx >> 4, d = idx & 15;
        bs_[gg * BPAD_ + d] = bias[gg * (J_ * D_) + j * D_ + d];
    }
    __syncthreads();

    // ---- pred[d][q]: id-chunks of 2 (12 x-floats live) to cap registers ----
    float pred[D_][QN_];
    {
        const float* bp = bs_ + g * BPAD_;
        #pragma unroll
        for (int d = 0; d < D_; ++d) {
            const float bv = bp[d];
            #pragma unroll
            for (int q = 0; q < QN_; ++q) pred[d][q] = bv;
        }
    }
    {
        const float* wrow = Ws + g * WPAD_;
        #pragma unroll 1
        for (int h = 0; h < 4; ++h) {       // ids 2h, 2h+1
            float xa[QN_], xc[QN_];
            #pragma unroll
            for (int m = 0; m < 3; ++m) {
                const float2 va = *(const float2*)(xb + (2 * h) * S_ + 2 * m);
                const float2 vc = *(const float2*)(xb + (2 * h + 1) * S_ + 2 * m);
                xa[2 * m] = va.x; xa[2 * m + 1] = va.y;
                xc[2 * m] = vc.x; xc[2 * m + 1] = vc.y;
            }
            #pragma unroll
            for (int d = 0; d < D_; ++d) {
                const float2 w = *(const float2*)(wrow + d * IND_ + 2 * h);
                #pragma unroll
                for (int q = 0; q < QN_; ++q)
                    pred[d][q] += w.x * xa[q] + w.y * xc[q];
            }
        }
    }

    // ---- routing ----
    float b_loc[QN_] = {0.f, 0.f, 0.f, 0.f, 0.f, 0.f};
    const float EPS = 2.220446049250313e-16f;
    const bool hib5 = (lane & 32) != 0, hib4 = (lane & 16) != 0;
    const bool hib3 = (lane & 8) != 0,  hib2 = (lane & 4) != 0;

    #pragma unroll
    for (int it = 0; it < 3; ++it) {
        const int k = it & 1;

        // un-normalized weights; it=0 has e=1 and exact denom = 1152
        float e[QN_];
        if (it == 0) {
            #pragma unroll
            for (int q = 0; q < QN_; ++q) e[q] = 1.f;
        } else {
            float se = 0.f;
            #pragma unroll
            for (int q = 0; q < QN_; ++q) { e[q] = __expf(b_loc[q]); se += e[q]; }
            #pragma unroll
            for (int off = 32; off >= 1; off >>= 1) se += __shfl_xor(se, off);
            if (lane == 0) sm[k][wid] = se;
        }

        // packed butterfly with lazy weighting (p[16] never materialized)
        float q8[8];
        #pragma unroll
        for (int dd = 0; dd < 8; ++dd) {
            float plo = e[0] * pred[dd][0], phi = e[0] * pred[dd + 8][0];
            #pragma unroll
            for (int q = 1; q < QN_; ++q) {
                plo += e[q] * pred[dd][q];
                phi += e[q] * pred[dd + 8][q];
            }
            const float snd = hib5 ? plo : phi;
            const float rr  = __shfl_xor(snd, 32);
            q8[dd] = (hib5 ? phi : plo) + rr;
        }
        float q4[4];
        #pragma unroll
        for (int dd = 0; dd < 4; ++dd) {
            const float snd = hib4 ? q8[dd] : q8[dd + 4];
            const float rr  = __shfl_xor(snd, 16);
            q4[dd] = (hib4 ? q8[dd + 4] : q8[dd]) + rr;
        }
        float q2[2];
        #pragma unroll
        for (int dd = 0; dd < 2; ++dd) {
            const float snd = hib3 ? q4[dd] : q4[dd + 2];
            const float rr  = __shfl_xor(snd, 8);
            q2[dd] = (hib3 ? q4[dd + 2] : q4[dd]) + rr;
        }
        float q1;
        {
            const float snd = hib2 ? q2[0] : q2[1];
            const float rr  = __shfl_xor(snd, 4);
            q1 = (hib2 ? q2[1] : q2[0]) + rr;
        }
        q1 += __shfl_xor(q1, 2);
        q1 += __shfl_xor(q1, 1);
        if ((lane & 3) == 0) pt[k][wid][lane >> 2] = q1;
        __syncthreads();                                   // barrier A

        const float denom = (it == 0) ? 1152.f
                                      : (sm[k][0] + sm[k][1] + sm[k][2]);

        if (t < D_) {
            sv[k][t] = pt[k][0][t] + pt[k][1][t] + pt[k][2][t];
        }
        __syncthreads();                                   // barrier B

        // ssq + (it<2) dot, consuming sv one float4 at a time (reg pressure)
        float ssq = 0.f;
        float acc[QN_] = {0.f, 0.f, 0.f, 0.f, 0.f, 0.f};
        #pragma unroll
        for (int blk = 0; blk < 4; ++blk) {
            const float4 s4 = ((const float4*)sv[k])[blk];
            ssq += s4.x * s4.x + s4.y * s4.y + s4.z * s4.z + s4.w * s4.w;
            if (it < 2) {
                #pragma unroll
                for (int q = 0; q < QN_; ++q)
                    acc[q] += s4.x * pred[4 * blk + 0][q] + s4.y * pred[4 * blk + 1][q]
                            + s4.z * pred[4 * blk + 2][q] + s4.w * pred[4 * blk + 3][q];
            }
        }
        const float alpha = 1.0f / denom;
        const float n2 = ssq * alpha * alpha;
        const float norm = sqrtf(n2);
        const float coeff = (n2 / (1.f + n2)) / (norm + EPS);
        const float beta = alpha * coeff;   // v[d] = sv[d] * beta

        if (it < 2) {
            #pragma unroll
            for (int q = 0; q < QN_; ++q) b_loc[q] += beta * acc[q];
        } else {
            if (t < D_) out[(size_t)bj * D_ + t] = sv[k][t] * beta;
        }
    }
}

extern "C" void kernel_launch(void* const* d_in, const int* in_sizes, int n_in,
                              void* d_out, int out_size, void* d_ws, size_t ws_size,
                              hipStream_t stream) {
    const float* x    = (const float*)d_in[0];
    const float* Wt   = (const float*)d_in[1];
    const float* bias = (const float*)d_in[2];
    float* out        = (float*)d_out;

    const int bs = in_sizes[0] / (G_ * IND_ * S_);   // 256
    dim3 grid(bs * J_);
    dim3 block(NT_);
    caps_route_kernel<<<grid, block, 0, stream>>>(x, Wt, bias, out);
}

// Round 9
// 26.583 us; speedup vs baseline: 3.2565x; 2.5737x over previous
//
#include <hip/hip_runtime.h>
#include <math.h>

// CapLayer fused, R9 (= R8 + denominator fix): pred is NEVER materialized.
// Routing factorizes through the group structure:
//   y[g,k] = sum_{i in g} e_i x[k,i]   (32x9 incl. C_g as k=8)
//   s[d]   = sum_{g,k} Wk[g,k,d] y[g,k]        (bias folded as k=8 row)
//   u[g,k] = beta * sum_d s[d] Wk[g,k,d]
//   b_i   += sum_k u[g,k] x[k,i]
// Per-thread state = x[8][9] + b[9]. NT=128 (2 waves), 4 lanes per group.
// R8 bug: denom reduce had a spurious *0.25 — after the quad reduce the
// bits-2..5 butterfly counts each group exactly ONCE (c-slice fixed).
// NO launch_bounds min-waves (R2/R3/R7: every cap spilled 60-350 MB scratch).

#define G_    32
#define J_    10
#define D_    16
#define NT_   128
#define GSW_  148
#define YS_   12

__global__ __launch_bounds__(NT_) void caps_route_kernel(
    const float* __restrict__ x,     // (b, g*8+k, s) flat b*9216 + g*288 + k*36 + s
    const float* __restrict__ Wt,    // (g, j*16+d, k) flat g*1280 + (j*16+d)*8 + k
    const float* __restrict__ bias,  // g*160 + j*16 + d
    float* __restrict__ out)         // (b, j, d)
{
    const int B = blockIdx.x, nwg = gridDim.x;
    const int bj = ((nwg & 7) == 0) ? (B & 7) * (nwg >> 3) + (B >> 3) : B;
    const int b = bj / J_, j = bj - b * J_;
    const int t = threadIdx.x;
    const int lane = t & 63, wid = t >> 6;
    const int g = t >> 2, c = t & 3;     // group 0..31, 4 lanes/group

    __shared__ float Wk[G_ * GSW_];      // 18.9 KB
    __shared__ float ylds[G_ * YS_];
    __shared__ __align__(16) float slds[D_];
    __shared__ float dsum[2];

    // ---- x preload: this thread owns s = 9c..9c+8 of group g ----
    float xv[8][9];
    {
        const float* xb = x + (size_t)b * 9216 + (size_t)g * 288 + 9 * c;
        #pragma unroll
        for (int k = 0; k < 8; ++k) {
            #pragma unroll
            for (int q = 0; q < 9; ++q) xv[k][q] = xb[k * 36 + q];
        }
    }

    // ---- stage Wk transposed ([g][k][d]) + bias as k=8 row ----
    #pragma unroll
    for (int rr = 0; rr < 4; ++rr) {
        const int idx = t + rr * NT_;
        const int gg = idx >> 4, d = idx & 15;
        const float* src = Wt + (size_t)gg * 1280 + j * 128 + d * 8;
        const float4 a0 = *(const float4*)(src);
        const float4 a1 = *(const float4*)(src + 4);
        float* dst = Wk + gg * GSW_ + d;
        dst[0]   = a0.x; dst[16]  = a0.y; dst[32]  = a0.z; dst[48]  = a0.w;
        dst[64]  = a1.x; dst[80]  = a1.y; dst[96]  = a1.z; dst[112] = a1.w;
        dst[128] = bias[gg * 160 + j * 16 + d];
    }
    __syncthreads();

    float b_loc[9] = {0.f,0.f,0.f,0.f,0.f,0.f,0.f,0.f,0.f};
    const float EPS = 2.220446049250313e-16f;

    #pragma unroll 1
    for (int it = 0; it < 3; ++it) {
        // ---- e-weighted x sums (per-thread partial over its 9 s's) ----
        float yp[8] = {0.f,0.f,0.f,0.f,0.f,0.f,0.f,0.f};
        float esum;
        if (it == 0) {
            #pragma unroll
            for (int q = 0; q < 9; ++q) {
                #pragma unroll
                for (int k = 0; k < 8; ++k) yp[k] += xv[k][q];
            }
            esum = 9.f;
        } else {
            esum = 0.f;
            #pragma unroll
            for (int q = 0; q < 9; ++q) {
                const float e = __expf(b_loc[q]);
                esum += e;
                #pragma unroll
                for (int k = 0; k < 8; ++k) yp[k] += e * xv[k][q];
            }
        }
        // 4-lane group reduce -> y[g,k], C_g
        #pragma unroll
        for (int k = 0; k < 8; ++k) {
            yp[k] += __shfl_xor(yp[k], 1);
            yp[k] += __shfl_xor(yp[k], 2);
        }
        esum += __shfl_xor(esum, 1);
        esum += __shfl_xor(esum, 2);
        if (c == 0) {
            #pragma unroll
            for (int k = 0; k < 8; ++k) ylds[g * YS_ + k] = yp[k];
            ylds[g * YS_ + 8] = esum;            // C_g
        }
        // denominator: butterfly over bits 2..5 sums the wave's 16 distinct
        // groups exactly once each (c-slice fixed) -> NO scaling factor
        float ws = esum;
        ws += __shfl_xor(ws, 4);  ws += __shfl_xor(ws, 8);
        ws += __shfl_xor(ws, 16); ws += __shfl_xor(ws, 32);
        if (lane == 0) dsum[wid] = ws;
        __syncthreads();                          // barrier 1
        const float denom = dsum[0] + dsum[1];

        // ---- s[d] = sum_{g,k} Wk[g][k][d] * y[g][k]  (incl. bias*C_g) ----
        {
            const int d = t >> 3, gg0 = t & 7;
            float sp = 0.f;
            #pragma unroll
            for (int gi = 0; gi < 4; ++gi) {
                const int gg = gg0 + 8 * gi;
                const float* wr = Wk + gg * GSW_ + d;
                const float* yr = ylds + gg * YS_;
                #pragma unroll
                for (int k = 0; k < 9; ++k) sp += wr[k * 16] * yr[k];
            }
            sp += __shfl_xor(sp, 1); sp += __shfl_xor(sp, 2); sp += __shfl_xor(sp, 4);
            if ((t & 7) == 0) slds[d] = sp;
        }
        __syncthreads();                          // barrier 2

        // ---- squash factors (redundant per-thread; 16 broadcast reads) ----
        float s16[16];
        #pragma unroll
        for (int m = 0; m < 4; ++m) {
            const float4 s4 = ((const float4*)slds)[m];
            s16[4*m] = s4.x; s16[4*m+1] = s4.y; s16[4*m+2] = s4.z; s16[4*m+3] = s4.w;
        }
        float ssq = 0.f;
        #pragma unroll
        for (int d = 0; d < 16; ++d) ssq += s16[d] * s16[d];
        const float alpha = 1.f / denom;
        const float n2    = ssq * alpha * alpha;
        const float nrm   = sqrtf(n2);
        const float coeff = (n2 / (1.f + n2)) / (nrm + EPS);
        const float beta  = alpha * coeff;        // v[d] = s_unnorm[d] * beta

        if (it < 2) {
            // ---- u[g,k] = beta * sum_d s16[d] Wk[g][k][d]; lane does k=c, c+4, 8 ----
            float ua = 0.f, ub = 0.f, u8 = 0.f;
            const float* wgc = Wk + g * GSW_;
            #pragma unroll
            for (int d = 0; d < 16; ++d) {
                ua += s16[d] * wgc[c * 16 + d];
                ub += s16[d] * wgc[(c + 4) * 16 + d];
                u8 += s16[d] * wgc[128 + d];
            }
            ua *= beta; ub *= beta; u8 *= beta;
            // gather u[0..7] across the 4-lane group (6 shfl)
            const float p1a = __shfl_xor(ua, 1);
            const float p1b = __shfl_xor(ub, 1);
            const bool  o1  = (c & 1) != 0;
            const float v0 = o1 ? p1a : ua;   // u[2m]
            const float v1 = o1 ? ua  : p1a;  // u[2m+1]
            const float v4 = o1 ? p1b : ub;
            const float v5 = o1 ? ub  : p1b;
            const float q0 = __shfl_xor(v0, 2);
            const float q1 = __shfl_xor(v1, 2);
            const float q4 = __shfl_xor(v4, 2);
            const float q5 = __shfl_xor(v5, 2);
            const bool  o2 = (c & 2) != 0;
            float u[8];
            u[0] = o2 ? q0 : v0;  u[1] = o2 ? q1 : v1;
            u[2] = o2 ? v0 : q0;  u[3] = o2 ? v1 : q1;
            u[4] = o2 ? q4 : v4;  u[5] = o2 ? q5 : v5;
            u[6] = o2 ? v4 : q4;  u[7] = o2 ? v5 : q5;
            // ---- b_i += u . x_i + u_bias ----
            #pragma unroll
            for (int q = 0; q < 9; ++q) {
                float acc = u8;
                #pragma unroll
                for (int k = 0; k < 8; ++k) acc += u[k] * xv[k][q];
                b_loc[q] += acc;
            }
        } else {
            if (t < D_) out[(size_t)bj * D_ + t] = slds[t] * beta;
        }
    }
}

extern "C" void kernel_launch(void* const* d_in, const int* in_sizes, int n_in,
                              void* d_out, int out_size, void* d_ws, size_t ws_size,
                              hipStream_t stream) {
    const float* x    = (const float*)d_in[0];
    const float* Wt   = (const float*)d_in[1];
    const float* bias = (const float*)d_in[2];
    float* out        = (float*)d_out;

    const int bs = in_sizes[0] / 9216;   // 256
    dim3 grid(bs * J_);                  // 2560
    dim3 block(NT_);
    caps_route_kernel<<<grid, block, 0, stream>>>(x, Wt, bias, out);
}